// Round 6
// baseline (844.394 us; speedup 1.0000x reference)
//
#include <hip/hip_runtime.h>
#include <hip/hip_bf16.h>

#define BB 64
#define EE 1000
#define FF 4000
#define LQ_ 30
#define TT 100
#define EMB_ 300
#define G4 400
#define EV_ 50007
#define VERY_NEG_ (-100000000000.0f)
#define EPS_ 1e-10f

typedef __attribute__((ext_vector_type(8))) short bf16x8;
typedef __attribute__((ext_vector_type(4))) float f32x4;

__device__ __forceinline__ float sigm(float x) { return 1.0f / (1.0f + expf(-x)); }

__device__ __forceinline__ unsigned short f2bf(float v) {
    __hip_bfloat16 h = __float2bfloat16(v);
    return *reinterpret_cast<unsigned short*>(&h);
}
__device__ __forceinline__ float bf2f(unsigned short s) {
    return __uint_as_float((unsigned)s << 16);
}

// ---------------------------------------------------------------- f32 -> bf16 bulk convert
__global__ void cvt_bf16_kernel(const float* __restrict__ in, unsigned short* __restrict__ out,
                                long n4) {
    long i = (long)blockIdx.x * 256 + threadIdx.x;
    if (i < n4) {
        float4 v = ((const float4*)in)[i];
        ushort4 o;
        o.x = f2bf(v.x); o.y = f2bf(v.y); o.z = f2bf(v.z); o.w = f2bf(v.w);
        ((ushort4*)out)[i] = o;
    }
}

// ---------------------------------------------------------------- transpose
__global__ void transpose_kernel(const float* __restrict__ in, float* __restrict__ out,
                                 int rows, int cols) {
    int i = blockIdx.x * 256 + threadIdx.x;
    if (i < rows * cols) {
        int r = i / cols, c = i % cols;
        out[c * rows + r] = in[i];
    }
}

// ---------------------------------------------------------------- xw: 4 tokens per block
__global__ __launch_bounds__(256)
void xw_kernel(const float* __restrict__ word_emb, const int* __restrict__ qtext,
               const float* __restrict__ WihT, const float* __restrict__ bih,
               const float* __restrict__ bhh, float* __restrict__ xw) {
    int bs0 = blockIdx.x * 4;
    __shared__ float x[4][EMB_];
    int tid = threadIdx.x;
    for (int i = tid; i < 4 * EMB_; i += 256) {
        int s = i / EMB_, k = i % EMB_;
        x[s][k] = word_emb[(long)qtext[bs0 + s] * EMB_ + k];
    }
    __syncthreads();
    for (int g = tid; g < G4; g += 256) {
        float b0 = bih[g] + bhh[g];
        float a0 = b0, a1 = b0, a2 = b0, a3 = b0;
        #pragma unroll 4
        for (int k = 0; k < EMB_; ++k) {
            float wv = WihT[k * G4 + g];
            a0 += x[0][k] * wv; a1 += x[1][k] * wv;
            a2 += x[2][k] * wv; a3 += x[3][k] * wv;
        }
        xw[(long)(bs0 + 0) * G4 + g] = a0;
        xw[(long)(bs0 + 1) * G4 + g] = a1;
        xw[(long)(bs0 + 2) * G4 + g] = a2;
        xw[(long)(bs0 + 3) * G4 + g] = a3;
    }
}

// ---------------------------------------------------------------- LSTM: weights in registers
__global__ __launch_bounds__(512)
void lstm_kernel(const float* __restrict__ xw, const float* __restrict__ Whh,
                 float* __restrict__ qh_emb, float* __restrict__ qnode) {
    int b = blockIdx.x, tid = threadIdx.x;
    __shared__ __align__(16) float hs[TT];
    __shared__ float cs[TT];
    __shared__ float gs[G4];
    float4 w[25];
    if (tid < G4) {
        const float4* wr = (const float4*)(Whh + (long)tid * TT);
        #pragma unroll
        for (int j = 0; j < 25; ++j) w[j] = wr[j];
    }
    if (tid < TT) { hs[tid] = 0.f; cs[tid] = 0.f; }
    __syncthreads();
    for (int s = 0; s < LQ_; ++s) {
        if (tid < G4) {
            const float4* hv4 = (const float4*)hs;
            float a0 = 0.f, a1 = 0.f, a2 = 0.f, a3 = 0.f;
            #pragma unroll
            for (int j = 0; j < 25; ++j) {
                float4 hv = hv4[j];
                a0 += hv.x * w[j].x; a1 += hv.y * w[j].y;
                a2 += hv.z * w[j].z; a3 += hv.w * w[j].w;
            }
            gs[tid] = xw[((long)b * LQ_ + s) * G4 + tid] + (a0 + a1) + (a2 + a3);
        }
        __syncthreads();
        if (tid < TT) {
            float ci = sigm(gs[TT + tid]) * cs[tid] + sigm(gs[tid]) * tanhf(gs[2 * TT + tid]);
            float hi = sigm(gs[3 * TT + tid]) * tanhf(ci);
            cs[tid] = ci;
            hs[tid] = hi;
            qh_emb[((long)b * LQ_ + s) * TT + tid] = hi;
            if (s == LQ_ - 1) qnode[b * TT + tid] = hi;
        }
        __syncthreads();
    }
}

// ---------------------------------------------------------------- multi-output MFMA GEMM
struct GOut {
    const float* W; int wstride;
    const float* bias;
    const float* bscale;
    const unsigned short* addb;   // bf16 add matrix (or null)
    const float* addf;            // f32 add matrix (or null)
    const float* cvec;            // per-batch row vector (or null)
    void* Y; int y_bf16; int relu;
};
struct GArgs {
    const void* X; int x_bf16;
    const int* gidx;
    long rows;
    int nw;
    GOut o[3];
};

__global__ __launch_bounds__(256)
void gemm_multi_kernel(GArgs a) {
    __shared__ __align__(16) short sX[64 * 136];    // 17408 B
    __shared__ __align__(16) short sW[112 * 136];   // 30464 B; aliased by sOut (26624 B)
    float* sOut = (float*)sW;
    int tid = threadIdx.x;
    long r0 = (long)blockIdx.x * 64;
    // ---- stage X
    for (int i = tid; i < 64 * 25; i += 256) {
        int r = i / 25, c = i % 25;
        long rr = r0 + r;
        ushort4 v; v.x = 0; v.y = 0; v.z = 0; v.w = 0;
        if (rr < a.rows) {
            long xr = a.gidx ? (long)a.gidx[rr] : rr;
            if (a.x_bf16) {
                v = *(const ushort4*)((const unsigned short*)a.X + xr * TT + c * 4);
            } else {
                float4 f = *(const float4*)((const float*)a.X + xr * TT + c * 4);
                v.x = f2bf(f.x); v.y = f2bf(f.y); v.z = f2bf(f.z); v.w = f2bf(f.w);
            }
        }
        *(ushort4*)&sX[r * 136 + c * 4] = v;
    }
    for (int i = tid; i < 64 * 28; i += 256) {       // zero k-pad [100,128)
        int r = i / 28, k = TT + i % 28;
        sX[r * 136 + k] = 0;
    }
    int lane = tid & 63, wv = tid >> 6;
    int arow = lane & 15, agrp = lane >> 4;
    int t_lo = lane & 15, r_hi = (lane >> 4) * 4;
    #pragma unroll
    for (int w = 0; w < 3; ++w) {
        if (w >= a.nw) break;
        for (int i = tid; i < 112 * 32; i += 256) {
            int t = i / 32, k = (i % 32) * 4;
            ushort4 v; v.x = 0; v.y = 0; v.z = 0; v.w = 0;
            if (t < TT && k < TT) {
                float4 f = *(const float4*)(a.o[w].W + (long)t * a.o[w].wstride + k);
                v.x = f2bf(f.x); v.y = f2bf(f.y); v.z = f2bf(f.z); v.w = f2bf(f.w);
            }
            *(ushort4*)&sW[t * 136 + k] = v;
        }
        __syncthreads();
        f32x4 acc[7];
        #pragma unroll
        for (int n = 0; n < 7; ++n) acc[n] = (f32x4){0.f, 0.f, 0.f, 0.f};
        #pragma unroll
        for (int kk = 0; kk < 4; ++kk) {
            bf16x8 av = *(const bf16x8*)&sX[(wv * 16 + arow) * 136 + kk * 32 + agrp * 8];
            #pragma unroll
            for (int n = 0; n < 7; ++n) {
                bf16x8 bv = *(const bf16x8*)&sW[(n * 16 + arow) * 136 + kk * 32 + agrp * 8];
                acc[n] = __builtin_amdgcn_mfma_f32_16x16x32_bf16(av, bv, acc[n], 0, 0, 0);
            }
        }
        __syncthreads();   // MFMA reads of sW done before sOut overwrite
        #pragma unroll
        for (int n = 0; n < 7; ++n) {
            int t = n * 16 + t_lo;
            if (t < TT) {
                #pragma unroll
                for (int j = 0; j < 4; ++j)
                    sOut[(wv * 16 + r_hi + j) * 104 + t] = acc[n][j];
            }
        }
        __syncthreads();
        for (int i = tid; i < 64 * 25; i += 256) {
            int r = i / 25, c = i % 25;
            long rr = r0 + r;
            if (rr < a.rows) {
                float4 v = *(float4*)&sOut[r * 104 + c * 4];
                if (a.o[w].bias) {
                    float bs = a.o[w].bscale ? a.o[w].bscale[rr] : 1.f;
                    float4 bv = *(const float4*)(a.o[w].bias + c * 4);
                    v.x += bv.x * bs; v.y += bv.y * bs; v.z += bv.z * bs; v.w += bv.w * bs;
                }
                if (a.o[w].addb) {
                    ushort4 ad = *(const ushort4*)(a.o[w].addb + rr * TT + c * 4);
                    v.x += bf2f(ad.x); v.y += bf2f(ad.y); v.z += bf2f(ad.z); v.w += bf2f(ad.w);
                }
                if (a.o[w].addf) {
                    float4 ad = *(const float4*)(a.o[w].addf + rr * TT + c * 4);
                    v.x += ad.x; v.y += ad.y; v.z += ad.z; v.w += ad.w;
                }
                if (a.o[w].cvec) {
                    float4 cv = *(const float4*)(a.o[w].cvec + (long)(rr / EE) * TT + c * 4);
                    v.x += cv.x; v.y += cv.y; v.z += cv.z; v.w += cv.w;
                }
                if (a.o[w].relu) {
                    v.x = fmaxf(v.x, 0.f); v.y = fmaxf(v.y, 0.f);
                    v.z = fmaxf(v.z, 0.f); v.w = fmaxf(v.w, 0.f);
                }
                if (a.o[w].y_bf16) {
                    ushort4 ov;
                    ov.x = f2bf(v.x); ov.y = f2bf(v.y); ov.z = f2bf(v.z); ov.w = f2bf(v.w);
                    *(ushort4*)((unsigned short*)a.o[w].Y + rr * TT + c * 4) = ov;
                } else {
                    *(float4*)((float*)a.o[w].Y + rr * TT + c * 4) = v;
                }
            }
        }
        __syncthreads();
    }
}

// ---------------------------------------------------------------- compose: C = A @ B, cb = A@ab + bb
__global__ __launch_bounds__(128)
void compose_kernel(const float* __restrict__ A, const float* __restrict__ B,
                    const float* __restrict__ ab, const float* __restrict__ bb,
                    float* __restrict__ C, float* __restrict__ cb) {
    int i = blockIdx.x, j = threadIdx.x;
    __shared__ float arow[TT];
    if (j < TT) arow[j] = A[i * TT + j];
    __syncthreads();
    if (j < TT) {
        float acc = 0.f;
        for (int k = 0; k < TT; ++k) acc += arow[k] * B[k * TT + j];
        C[i * TT + j] = acc;
    }
    if (j == 0) {
        float acc = bb[i];
        for (int k = 0; k < TT; ++k) acc += arow[k] * ab[k];
        cb[i] = acc;
    }
}

// ---------------------------------------------------------------- Wsc (fused sim/softmax/att)
__global__ __launch_bounds__(256)
void wsc_kernel(const float* __restrict__ qh_emb, const int* __restrict__ qtext,
                const unsigned short* __restrict__ ent_f, const int* __restrict__ rel,
                float* __restrict__ Wsc) {
    int b = blockIdx.x >> 4;
    int chunk = blockIdx.x & 15;
    __shared__ __align__(16) float qh[LQ_ * TT];
    __shared__ float msk[LQ_];
    for (int i = threadIdx.x; i < LQ_ * TT; i += 256) qh[i] = qh_emb[(long)b * LQ_ * TT + i];
    for (int i = threadIdx.x; i < LQ_; i += 256)
        msk[i] = (qtext[b * LQ_ + i] != 0) ? 0.f : VERY_NEG_;
    __syncthreads();
    int f = chunk * 256 + threadIdx.x;
    if (f >= FF) return;
    long bf = (long)b * FF + f;
    const unsigned short* fr = ent_f + (long)rel[bf] * TT;
    float sim[LQ_];
    #pragma unroll
    for (int l = 0; l < LQ_; ++l) sim[l] = 0.f;
    for (int kq = 0; kq < 25; ++kq) {
        ushort4 x4 = *(const ushort4*)(fr + kq * 4);
        float x0 = bf2f(x4.x), x1 = bf2f(x4.y), x2 = bf2f(x4.z), x3 = bf2f(x4.w);
        #pragma unroll
        for (int l = 0; l < LQ_; ++l) {
            float4 q = ((const float4*)(qh + l * TT))[kq];
            sim[l] += x0 * q.x + x1 * q.y + x2 * q.z + x3 * q.w;
        }
    }
    float mx = -INFINITY;
    #pragma unroll
    for (int l = 0; l < LQ_; ++l) {
        sim[l] *= 0.1f;  // /sqrt(100)
        mx = fmaxf(mx, sim[l] + msk[l]);
    }
    float ssum = 0.f, wsum = 0.f;
    #pragma unroll
    for (int l = 0; l < LQ_; ++l) {
        float p = expf(sim[l] + msk[l] - mx);
        ssum += p;
        wsum += p * sim[l];
    }
    Wsc[bf] = wsum / ssum;
}

// ---------------------------------------------------------------- row max over facts
__global__ __launch_bounds__(256)
void rowmax_kernel(const float* __restrict__ Wsc, float* __restrict__ bmax) {
    int b = blockIdx.x, tid = threadIdx.x;
    __shared__ float red[256];
    float m = -INFINITY;
    for (int f = tid; f < FF; f += 256) m = fmaxf(m, Wsc[(long)b * FF + f]);
    red[tid] = m;
    __syncthreads();
    for (int s = 128; s; s >>= 1) {
        if (tid < s) red[tid] = fmaxf(red[tid], red[tid + s]);
        __syncthreads();
    }
    if (tid == 0) bmax[b] = red[0];
}

// ---------------------------------------------------------------- W_tilde + e2f_softmax scatter + tail counts
__global__ __launch_bounds__(256)
void wtilde_kernel(const float* __restrict__ Wsc, const float* __restrict__ bmax,
                   const int* __restrict__ head, const int* __restrict__ tail,
                   float* __restrict__ W_tilde, float* __restrict__ e2f_sm,
                   float* __restrict__ cnt) {
    int idx = blockIdx.x * 256 + threadIdx.x;
    if (idx >= BB * FF) return;
    int b = idx / FF;
    float wt = expf(Wsc[idx] - bmax[b]);
    W_tilde[idx] = wt;
    atomicAdd(&e2f_sm[(long)b * EE + head[idx]], wt);
    atomicAdd(&cnt[(long)b * EE + tail[idx]], 1.f);
}

// ---------------------------------------------------------------- per-batch exclusive scan of cnt -> offs
__global__ __launch_bounds__(256)
void scan_kernel(const float* __restrict__ cnt, int* __restrict__ offs) {
    int b = blockIdx.x, tid = threadIdx.x;
    __shared__ int ls[256];
    int c0 = 0, c1 = 0, c2 = 0, c3 = 0;
    int start = tid * 4;
    if (start + 0 < EE) c0 = (int)cnt[(long)b * EE + start + 0];
    if (start + 1 < EE) c1 = (int)cnt[(long)b * EE + start + 1];
    if (start + 2 < EE) c2 = (int)cnt[(long)b * EE + start + 2];
    if (start + 3 < EE) c3 = (int)cnt[(long)b * EE + start + 3];
    int s = c0 + c1 + c2 + c3;
    ls[tid] = s;
    __syncthreads();
    for (int d = 1; d < 256; d <<= 1) {
        int v = (tid >= d) ? ls[tid - d] : 0;
        __syncthreads();
        ls[tid] += v;
        __syncthreads();
    }
    int excl = ls[tid] - s + b * FF;   // each batch owns exactly FF facts
    if (start + 0 < EE) { offs[(long)b * EE + start + 0] = excl; excl += c0; }
    if (start + 1 < EE) { offs[(long)b * EE + start + 1] = excl; excl += c1; }
    if (start + 2 < EE) { offs[(long)b * EE + start + 2] = excl; excl += c2; }
    if (start + 3 < EE) { offs[(long)b * EE + start + 3] = excl; excl += c3; }
    if (b == BB - 1 && tid == 255) offs[BB * EE] = BB * FF;
}

// ---------------------------------------------------------------- scatter facts into tail-sorted perm
__global__ __launch_bounds__(256)
void sortfacts_kernel(const int* __restrict__ tail, const int* __restrict__ offs,
                      int* __restrict__ fillc, int* __restrict__ perm) {
    int idx = blockIdx.x * 256 + threadIdx.x;
    if (idx >= BB * FF) return;
    int b = idx / FF;
    int bin = b * EE + tail[idx];
    int pos = offs[bin] + atomicAdd(&fillc[bin], 1);
    perm[pos] = idx;
}

// ---------------------------------------------------------------- segmented e2f: per (b,tail) bin accumulate
__global__ __launch_bounds__(256)
void e2f_sorted_kernel(const unsigned short* __restrict__ kbs_tab,
                       const unsigned short* __restrict__ kbh,
                       const float* __restrict__ W_tilde, const float* __restrict__ pr,
                       const float* __restrict__ e2f_sm,
                       const int* __restrict__ rel, const int* __restrict__ head,
                       const int* __restrict__ offs, const int* __restrict__ perm,
                       unsigned short* __restrict__ eaccb, float* __restrict__ pr_acc) {
    int grp = threadIdx.x >> 7;        // 2 bins per block
    int t = threadIdx.x & 127;
    int bin = blockIdx.x * 2 + grp;
    if (bin >= BB * EE) return;
    int b = bin / EE;
    int j0 = offs[bin], j1 = offs[bin + 1];
    float acc = 0.f, nsum = 0.f;
    for (int j = j0; j < j1; ++j) {
        int f = perm[j];
        long bh = (long)b * EE + head[f];
        float n = W_tilde[f] * pr[bh] / fmaxf(e2f_sm[bh], EPS_);
        if (n != 0.f) {
            nsum += n;
            if (t < TT) {
                float v = bf2f(kbs_tab[(long)rel[f] * TT + t]) + bf2f(kbh[bh * TT + t]);
                acc += fmaxf(v, 0.f) * n;
            }
        }
    }
    if (t < TT) eaccb[(long)bin * TT + t] = f2bf(acc);
    if (t == TT) pr_acc[bin] = nsum;
}

// ---------------------------------------------------------------- pagerank update
__global__ void pr_update_kernel(const float* __restrict__ pr_acc, float* __restrict__ pr,
                                 float* __restrict__ out2) {
    int i = blockIdx.x * 256 + threadIdx.x;
    if (i < BB * EE) {
        float v = 0.8f * pr_acc[i] + 0.2f * pr[i];
        pr[i] = v;
        if (out2) out2[i] = v;
    }
}

// ---------------------------------------------------------------- weighted reductions s1,s3,prsum
#define RCH 50
__global__ __launch_bounds__(128)
void reduce_kernel(const float* __restrict__ pr, const unsigned short* __restrict__ ent,
                   const int* __restrict__ gidx, const unsigned short* __restrict__ f2e,
                   float* __restrict__ s1, float* __restrict__ s3, float* __restrict__ prsum) {
    int b = blockIdx.x / (EE / RCH), ch = blockIdx.x % (EE / RCH);
    int e0 = ch * RCH, tid = threadIdx.x;
    __shared__ float prl[RCH];
    __shared__ long erow[RCH];
    if (tid < RCH) {
        long idx = (long)b * EE + e0 + tid;
        prl[tid] = pr[idx];
        erow[tid] = gidx ? (long)gidx[idx] : idx;
    }
    __syncthreads();
    if (tid == 0) {
        float s = 0.f;
        for (int e = 0; e < RCH; ++e) s += prl[e];
        if (s != 0.f) atomicAdd(&prsum[b], s);
    }
    if (tid < TT) {
        float a1 = 0.f, a3 = 0.f;
        for (int e = 0; e < RCH; ++e) {
            float p = prl[e];
            if (p != 0.f) {
                a1 += p * bf2f(ent[erow[e] * TT + tid]);
                a3 += p * bf2f(f2e[((long)b * EE + e0 + e) * TT + tid]);
            }
        }
        atomicAdd(&s1[b * TT + tid], a1);
        atomicAdd(&s3[b * TT + tid], a3);
    }
}

// ---------------------------------------------------------------- per-layer tiny: q2e_vec + cvecs
__global__ __launch_bounds__(128)
void qvec_kernel(const float* __restrict__ qnode,
                 const float* __restrict__ q2eW, const float* __restrict__ q2eb,
                 const float* __restrict__ e2eW, const float* __restrict__ e2eb,
                 const float* __restrict__ e2qW, const float* __restrict__ e2qb,
                 float* __restrict__ q2e_vec, float* __restrict__ cvec_e2e,
                 float* __restrict__ cvec_e2q) {
    int b = blockIdx.x, t = threadIdx.x;
    __shared__ float qn[TT], qv[TT];
    if (t < TT) qn[t] = qnode[b * TT + t];
    __syncthreads();
    if (t < TT) {
        float acc = q2eb[t];
        for (int k = 0; k < TT; ++k) acc += qn[k] * q2eW[t * TT + k];
        qv[t] = acc;
        q2e_vec[b * TT + t] = acc;
    }
    __syncthreads();
    if (t < TT) {
        float a1 = e2eb[t], a2 = e2qb[t];
        for (int k = 0; k < TT; ++k) {
            a1 += qv[k] * e2eW[(long)t * 300 + TT + k];
            a2 += qv[k] * e2qW[(long)t * 300 + TT + k];
        }
        cvec_e2e[b * TT + t] = a1;
        cvec_e2q[b * TT + t] = a2;
    }
}

// ---------------------------------------------------------------- qnode update
__global__ __launch_bounds__(128)
void qnode_kernel(const float* __restrict__ s1, const float* __restrict__ s3,
                  const float* __restrict__ prsum, const float* __restrict__ cvec_e2q,
                  const float* __restrict__ e2qW, float* __restrict__ qnode,
                  float* __restrict__ out2) {
    int b = blockIdx.x, t = threadIdx.x;
    __shared__ float s1l[TT], s3l[TT];
    if (t < TT) { s1l[t] = s1[b * TT + t]; s3l[t] = s3[b * TT + t]; }
    __syncthreads();
    if (t < TT) {
        float acc = prsum[b] * cvec_e2q[b * TT + t];
        const float* wr = e2qW + (long)t * 300;
        for (int k = 0; k < TT; ++k) acc += s1l[k] * wr[k] + s3l[k] * wr[200 + k];
        qnode[b * TT + t] = acc;
        if (out2) out2[b * TT + t] = acc;
    }
}

// ================================================================ host
extern "C" void kernel_launch(void* const* d_in, const int* in_sizes, int n_in,
                              void* d_out, int out_size, void* d_ws, size_t ws_size,
                              hipStream_t stream) {
    const float* word_emb   = (const float*)d_in[0];
    const float* entity_emb = (const float*)d_in[1];
    const float* ent_W      = (const float*)d_in[2];
    const float* ent_b      = (const float*)d_in[3];
    const float* lstm_Wih   = (const float*)d_in[4];
    const float* lstm_Whh   = (const float*)d_in[5];
    const float* lstm_bih   = (const float*)d_in[6];
    const float* lstm_bhh   = (const float*)d_in[7];
    const float* q2e_W      = (const float*)d_in[8];
    const float* q2e_b      = (const float*)d_in[9];
    const float* e2q_W      = (const float*)d_in[10];
    const float* e2q_b      = (const float*)d_in[11];
    const float* e2e_W      = (const float*)d_in[12];
    const float* e2e_b      = (const float*)d_in[13];
    const float* kbh_W      = (const float*)d_in[14];
    const float* kbh_b      = (const float*)d_in[15];
    const float* kbt_W      = (const float*)d_in[16];
    const float* kbt_b      = (const float*)d_in[17];
    const float* kbs_W      = (const float*)d_in[18];
    const float* kbs_b      = (const float*)d_in[19];
    const float* q2e_adj    = (const float*)d_in[20];
    const int* query_text   = (const int*)d_in[21];
    const int* local_entity = (const int*)d_in[22];
    const int* kb_fact_rel  = (const int*)d_in[23];
    const int* head_idx     = (const int*)d_in[24];
    const int* tail_idx     = (const int*)d_in[25];
    float* out = (float*)d_out;

    char* base = (char*)d_ws;
    size_t off = 0;
    auto alloc = [&](size_t bytes) {
        void* p = base + off;
        off = (off + bytes + 255) & ~(size_t)255;
        return p;
    };
    const size_t NE = (size_t)BB * EE;          // 64000
    unsigned short* emb_bf  = (unsigned short*)alloc((size_t)EV_ * TT * 2);
    unsigned short* ent_f   = (unsigned short*)alloc((size_t)EV_ * TT * 2);
    unsigned short* kbs0    = (unsigned short*)alloc((size_t)EV_ * TT * 2);
    unsigned short* kbs1    = (unsigned short*)alloc((size_t)EV_ * TT * 2);
    unsigned short* entB    = (unsigned short*)alloc(NE * TT * 2);
    unsigned short* kbh_bf  = (unsigned short*)alloc(NE * TT * 2);   // aliased as f2e
    unsigned short* kbs_e   = (unsigned short*)alloc(NE * TT * 2);
    unsigned short* tmp     = (unsigned short*)alloc(NE * TT * 2);
    unsigned short* eaccb   = (unsigned short*)alloc(NE * TT * 2);
    float* pr_acc           = (float*)alloc(NE * 4);
    float* xw               = (float*)alloc((size_t)BB * LQ_ * G4 * 4);
    float* qh_emb           = (float*)alloc((size_t)BB * LQ_ * TT * 4);
    float* WihT             = (float*)alloc((size_t)G4 * EMB_ * 4);
    float* Wsc              = (float*)alloc((size_t)BB * FF * 4);
    float* W_tilde          = (float*)alloc((size_t)BB * FF * 4);
    float* bmaxb            = (float*)alloc(BB * 4);
    float* e2f_sm           = (float*)alloc(NE * 4);                 // contiguous with cnt
    float* cnt              = (float*)alloc(NE * 4);
    float* pr               = (float*)alloc(NE * 4);
    float* qnode            = (float*)alloc((size_t)BB * TT * 4);
    float* q2e_vec          = (float*)alloc((size_t)BB * TT * 4);
    float* cvec_e2e         = (float*)alloc((size_t)BB * TT * 4);
    float* cvec_e2q         = (float*)alloc((size_t)BB * TT * 4);
    float* s1               = (float*)alloc((size_t)BB * TT * 4);    // s1,s3,prsum contiguous
    float* s3               = (float*)alloc((size_t)BB * TT * 4);
    float* prsum            = (float*)alloc(BB * 4);
    float* Ckbs0            = (float*)alloc((size_t)TT * TT * 4);
    float* Ckbs1            = (float*)alloc((size_t)TT * TT * 4);
    float* cb0              = (float*)alloc(TT * 4);
    float* cb1              = (float*)alloc(TT * 4);
    int* offs               = (int*)alloc((NE + 1) * 4);
    int* fillc              = (int*)alloc(NE * 4);
    int* perm               = (int*)alloc((size_t)BB * FF * 4);
    unsigned short* f2e = kbh_bf;  // alias: kbh dead after e2f_sorted

    // ---- LSTM path
    transpose_kernel<<<(G4 * EMB_ + 255) / 256, 256, 0, stream>>>(lstm_Wih, WihT, G4, EMB_);
    xw_kernel<<<BB * LQ_ / 4, 256, 0, stream>>>(word_emb, query_text, WihT, lstm_bih, lstm_bhh, xw);
    lstm_kernel<<<BB, 512, 0, stream>>>(xw, lstm_Whh, qh_emb, qnode);

    // ---- composed vocab tables: ent_f, kbs0, kbs1 in ONE pass over bf16 entity_emb
    cvt_bf16_kernel<<<(EV_ * TT / 4 + 255) / 256, 256, 0, stream>>>(entity_emb, emb_bf,
                                                                    (long)EV_ * TT / 4);
    compose_kernel<<<TT, 128, 0, stream>>>(kbs_W, ent_W, ent_b, kbs_b, Ckbs0, cb0);
    compose_kernel<<<TT, 128, 0, stream>>>(kbs_W + TT * TT, ent_W, ent_b, kbs_b + TT,
                                           Ckbs1, cb1);
    {
        GArgs g{};
        g.X = emb_bf; g.x_bf16 = 1; g.gidx = nullptr; g.rows = EV_; g.nw = 3;
        g.o[0].W = ent_W; g.o[0].wstride = TT; g.o[0].bias = ent_b;
        g.o[0].Y = ent_f; g.o[0].y_bf16 = 1;
        g.o[1].W = Ckbs0; g.o[1].wstride = TT; g.o[1].bias = cb0;
        g.o[1].Y = kbs0; g.o[1].y_bf16 = 1;
        g.o[2].W = Ckbs1; g.o[2].wstride = TT; g.o[2].bias = cb1;
        g.o[2].Y = kbs1; g.o[2].y_bf16 = 1;
        gemm_multi_kernel<<<(EV_ + 63) / 64, 256, 0, stream>>>(g);
    }

    // ---- attention scores -> W_tilde, e2f_softmax, counts
    wsc_kernel<<<BB * 16, 256, 0, stream>>>(qh_emb, query_text, ent_f, kb_fact_rel, Wsc);
    rowmax_kernel<<<BB, 256, 0, stream>>>(Wsc, bmaxb);
    hipMemsetAsync(e2f_sm, 0, 2 * NE * 4, stream);
    wtilde_kernel<<<(BB * FF + 255) / 256, 256, 0, stream>>>(Wsc, bmaxb, head_idx, tail_idx,
                                                             W_tilde, e2f_sm, cnt);
    hipMemcpyAsync(pr, q2e_adj, NE * 4, hipMemcpyDeviceToDevice, stream);

    // ---- tail-sort the fact list (once; indices are layer-invariant)
    scan_kernel<<<BB, 256, 0, stream>>>(cnt, offs);
    hipMemsetAsync(fillc, 0, NE * 4, stream);
    sortfacts_kernel<<<(BB * FF + 255) / 256, 256, 0, stream>>>(tail_idx, offs, fillc, perm);

    // ---- GNN layers
    for (int i = 0; i < 2; ++i) {
        const unsigned short* kbs_tab = i ? kbs1 : kbs0;
        qvec_kernel<<<BB, 128, 0, stream>>>(qnode, q2e_W + i * TT * TT, q2e_b + i * TT,
                                            e2e_W + i * TT * 300, e2e_b + i * TT,
                                            e2q_W + i * TT * 300, e2q_b + i * TT,
                                            q2e_vec, cvec_e2e, cvec_e2q);
        // one pass over ent_in: kbh, kbs_e, e2e-part1(tmp)
        {
            GArgs g{};
            g.X = i ? (const void*)entB : (const void*)ent_f;
            g.x_bf16 = 1;
            g.gidx = i ? nullptr : local_entity;
            g.rows = (long)NE; g.nw = 3;
            g.o[0].W = kbh_W + i * TT * TT; g.o[0].wstride = TT; g.o[0].bias = kbh_b + i * TT;
            g.o[0].Y = kbh_bf; g.o[0].y_bf16 = 1;
            g.o[1].W = kbs_W + i * TT * TT; g.o[1].wstride = TT; g.o[1].bias = kbs_b + i * TT;
            g.o[1].Y = kbs_e; g.o[1].y_bf16 = 1;
            g.o[2].W = e2e_W + i * TT * 300; g.o[2].wstride = 300;
            g.o[2].Y = tmp; g.o[2].y_bf16 = 1;
            gemm_multi_kernel<<<(int)(NE / 64), 256, 0, stream>>>(g);
        }
        // segmented e2f: writes every (b,e) row of eaccb + pr_acc (no memset needed)
        e2f_sorted_kernel<<<(int)(NE / 2), 256, 0, stream>>>(
            kbs_tab, kbh_bf, W_tilde, pr, e2f_sm, kb_fact_rel, head_idx, offs, perm,
            eaccb, pr_acc);
        // f2e = relu(kbs_e + eacc@kbt.T + kbt_b*cnt)   (f2e aliases kbh_bf)
        {
            GArgs g{};
            g.X = eaccb; g.x_bf16 = 1; g.gidx = nullptr; g.rows = (long)NE; g.nw = 1;
            g.o[0].W = kbt_W + i * TT * TT; g.o[0].wstride = TT;
            g.o[0].bias = kbt_b + i * TT; g.o[0].bscale = cnt;
            g.o[0].addb = kbs_e;
            g.o[0].Y = (void*)f2e; g.o[0].y_bf16 = 1; g.o[0].relu = 1;
            gemm_multi_kernel<<<(int)(NE / 64), 256, 0, stream>>>(g);
        }
        pr_update_kernel<<<(int)((NE + 255) / 256), 256, 0, stream>>>(
            pr_acc, pr, (i == 1) ? out + 6406400 : nullptr);
        hipMemsetAsync(s1, 0, (size_t)(2 * BB * TT + BB) * 4, stream);
        reduce_kernel<<<BB * (EE / RCH), 128, 0, stream>>>(
            pr, i ? entB : ent_f, i ? nullptr : local_entity, f2e, s1, s3, prsum);
        qnode_kernel<<<BB, 128, 0, stream>>>(s1, s3, prsum, cvec_e2q, e2q_W + i * TT * 300,
                                             qnode, (i == 1) ? out + 6400000 : nullptr);
        // ent_out = relu(tmp + f2e@W3.T + cvec_e2e)
        {
            GArgs g{};
            g.X = f2e; g.x_bf16 = 1; g.gidx = nullptr; g.rows = (long)NE; g.nw = 1;
            g.o[0].W = e2e_W + i * TT * 300 + 200; g.o[0].wstride = 300;
            g.o[0].addb = tmp; g.o[0].cvec = cvec_e2e; g.o[0].relu = 1;
            g.o[0].Y = i ? (void*)out : (void*)entB; g.o[0].y_bf16 = i ? 0 : 1;
            gemm_multi_kernel<<<(int)(NE / 64), 256, 0, stream>>>(g);
        }
    }
}

// Round 7
// 781.448 us; speedup vs baseline: 1.0806x; 1.0806x over previous
//
#include <hip/hip_runtime.h>
#include <hip/hip_bf16.h>

#define BB 64
#define EE 1000
#define FF 4000
#define LQ_ 30
#define TT 100
#define EMB_ 300
#define G4 400
#define EV_ 50007
#define VERY_NEG_ (-100000000000.0f)
#define EPS_ 1e-10f

typedef __attribute__((ext_vector_type(8))) short bf16x8;
typedef __attribute__((ext_vector_type(4))) float f32x4;

__device__ __forceinline__ float sigm(float x) { return 1.0f / (1.0f + expf(-x)); }

__device__ __forceinline__ unsigned short f2bf(float v) {
    __hip_bfloat16 h = __float2bfloat16(v);
    return *reinterpret_cast<unsigned short*>(&h);
}
__device__ __forceinline__ float bf2f(unsigned short s) {
    return __uint_as_float((unsigned)s << 16);
}

// ---------------------------------------------------------------- f32 -> bf16 bulk convert
__global__ void cvt_bf16_kernel(const float* __restrict__ in, unsigned short* __restrict__ out,
                                long n4) {
    long i = (long)blockIdx.x * 256 + threadIdx.x;
    if (i < n4) {
        float4 v = ((const float4*)in)[i];
        ushort4 o;
        o.x = f2bf(v.x); o.y = f2bf(v.y); o.z = f2bf(v.z); o.w = f2bf(v.w);
        ((ushort4*)out)[i] = o;
    }
}

// ---------------------------------------------------------------- transpose
__global__ void transpose_kernel(const float* __restrict__ in, float* __restrict__ out,
                                 int rows, int cols) {
    int i = blockIdx.x * 256 + threadIdx.x;
    if (i < rows * cols) {
        int r = i / cols, c = i % cols;
        out[c * rows + r] = in[i];
    }
}

// ---------------------------------------------------------------- xw: 4 tokens per block
__global__ __launch_bounds__(256)
void xw_kernel(const float* __restrict__ word_emb, const int* __restrict__ qtext,
               const float* __restrict__ WihT, const float* __restrict__ bih,
               const float* __restrict__ bhh, float* __restrict__ xw) {
    int bs0 = blockIdx.x * 4;
    __shared__ float x[4][EMB_];
    int tid = threadIdx.x;
    for (int i = tid; i < 4 * EMB_; i += 256) {
        int s = i / EMB_, k = i % EMB_;
        x[s][k] = word_emb[(long)qtext[bs0 + s] * EMB_ + k];
    }
    __syncthreads();
    for (int g = tid; g < G4; g += 256) {
        float b0 = bih[g] + bhh[g];
        float a0 = b0, a1 = b0, a2 = b0, a3 = b0;
        #pragma unroll 4
        for (int k = 0; k < EMB_; ++k) {
            float wv = WihT[k * G4 + g];
            a0 += x[0][k] * wv; a1 += x[1][k] * wv;
            a2 += x[2][k] * wv; a3 += x[3][k] * wv;
        }
        xw[(long)(bs0 + 0) * G4 + g] = a0;
        xw[(long)(bs0 + 1) * G4 + g] = a1;
        xw[(long)(bs0 + 2) * G4 + g] = a2;
        xw[(long)(bs0 + 3) * G4 + g] = a3;
    }
}

// ---------------------------------------------------------------- LSTM: weights in registers
__global__ __launch_bounds__(512)
void lstm_kernel(const float* __restrict__ xw, const float* __restrict__ Whh,
                 float* __restrict__ qh_emb, float* __restrict__ qnode) {
    int b = blockIdx.x, tid = threadIdx.x;
    __shared__ __align__(16) float hs[TT];
    __shared__ float cs[TT];
    __shared__ float gs[G4];
    float4 w[25];
    if (tid < G4) {
        const float4* wr = (const float4*)(Whh + (long)tid * TT);
        #pragma unroll
        for (int j = 0; j < 25; ++j) w[j] = wr[j];
    }
    if (tid < TT) { hs[tid] = 0.f; cs[tid] = 0.f; }
    __syncthreads();
    for (int s = 0; s < LQ_; ++s) {
        if (tid < G4) {
            const float4* hv4 = (const float4*)hs;
            float a0 = 0.f, a1 = 0.f, a2 = 0.f, a3 = 0.f;
            #pragma unroll
            for (int j = 0; j < 25; ++j) {
                float4 hv = hv4[j];
                a0 += hv.x * w[j].x; a1 += hv.y * w[j].y;
                a2 += hv.z * w[j].z; a3 += hv.w * w[j].w;
            }
            gs[tid] = xw[((long)b * LQ_ + s) * G4 + tid] + (a0 + a1) + (a2 + a3);
        }
        __syncthreads();
        if (tid < TT) {
            float ci = sigm(gs[TT + tid]) * cs[tid] + sigm(gs[tid]) * tanhf(gs[2 * TT + tid]);
            float hi = sigm(gs[3 * TT + tid]) * tanhf(ci);
            cs[tid] = ci;
            hs[tid] = hi;
            qh_emb[((long)b * LQ_ + s) * TT + tid] = hi;
            if (s == LQ_ - 1) qnode[b * TT + tid] = hi;
        }
        __syncthreads();
    }
}

// ---------------------------------------------------------------- multi-output MFMA GEMM
struct GOut {
    const float* W; int wstride;
    const float* bias;
    const float* bscale;
    const unsigned short* addb;   // bf16 add matrix (or null)
    const float* addf;            // f32 add matrix (or null)
    const float* cvec;            // per-batch row vector (or null)
    void* Y; int y_bf16; int relu;
};
struct GArgs {
    const void* X; int x_bf16;
    const int* gidx;
    long rows;
    int nw;
    GOut o[3];
};

__global__ __launch_bounds__(256)
void gemm_multi_kernel(GArgs a) {
    __shared__ __align__(16) short sX[64 * 136];    // 17408 B
    __shared__ __align__(16) short sW[112 * 136];   // 30464 B; aliased by sOut (26624 B)
    float* sOut = (float*)sW;
    int tid = threadIdx.x;
    long r0 = (long)blockIdx.x * 64;
    // ---- stage X
    for (int i = tid; i < 64 * 25; i += 256) {
        int r = i / 25, c = i % 25;
        long rr = r0 + r;
        ushort4 v; v.x = 0; v.y = 0; v.z = 0; v.w = 0;
        if (rr < a.rows) {
            long xr = a.gidx ? (long)a.gidx[rr] : rr;
            if (a.x_bf16) {
                v = *(const ushort4*)((const unsigned short*)a.X + xr * TT + c * 4);
            } else {
                float4 f = *(const float4*)((const float*)a.X + xr * TT + c * 4);
                v.x = f2bf(f.x); v.y = f2bf(f.y); v.z = f2bf(f.z); v.w = f2bf(f.w);
            }
        }
        *(ushort4*)&sX[r * 136 + c * 4] = v;
    }
    for (int i = tid; i < 64 * 28; i += 256) {       // zero k-pad [100,128)
        int r = i / 28, k = TT + i % 28;
        sX[r * 136 + k] = 0;
    }
    int lane = tid & 63, wv = tid >> 6;
    int arow = lane & 15, agrp = lane >> 4;
    int t_lo = lane & 15, r_hi = (lane >> 4) * 4;
    #pragma unroll
    for (int w = 0; w < 3; ++w) {
        if (w >= a.nw) break;
        for (int i = tid; i < 112 * 32; i += 256) {
            int t = i / 32, k = (i % 32) * 4;
            ushort4 v; v.x = 0; v.y = 0; v.z = 0; v.w = 0;
            if (t < TT && k < TT) {
                float4 f = *(const float4*)(a.o[w].W + (long)t * a.o[w].wstride + k);
                v.x = f2bf(f.x); v.y = f2bf(f.y); v.z = f2bf(f.z); v.w = f2bf(f.w);
            }
            *(ushort4*)&sW[t * 136 + k] = v;
        }
        __syncthreads();
        f32x4 acc[7];
        #pragma unroll
        for (int n = 0; n < 7; ++n) acc[n] = (f32x4){0.f, 0.f, 0.f, 0.f};
        #pragma unroll
        for (int kk = 0; kk < 4; ++kk) {
            bf16x8 av = *(const bf16x8*)&sX[(wv * 16 + arow) * 136 + kk * 32 + agrp * 8];
            #pragma unroll
            for (int n = 0; n < 7; ++n) {
                bf16x8 bv = *(const bf16x8*)&sW[(n * 16 + arow) * 136 + kk * 32 + agrp * 8];
                acc[n] = __builtin_amdgcn_mfma_f32_16x16x32_bf16(av, bv, acc[n], 0, 0, 0);
            }
        }
        __syncthreads();   // MFMA reads of sW done before sOut overwrite
        #pragma unroll
        for (int n = 0; n < 7; ++n) {
            int t = n * 16 + t_lo;
            if (t < TT) {
                #pragma unroll
                for (int j = 0; j < 4; ++j)
                    sOut[(wv * 16 + r_hi + j) * 104 + t] = acc[n][j];
            }
        }
        __syncthreads();
        for (int i = tid; i < 64 * 25; i += 256) {
            int r = i / 25, c = i % 25;
            long rr = r0 + r;
            if (rr < a.rows) {
                float4 v = *(float4*)&sOut[r * 104 + c * 4];
                if (a.o[w].bias) {
                    float bs = a.o[w].bscale ? a.o[w].bscale[rr] : 1.f;
                    float4 bv = *(const float4*)(a.o[w].bias + c * 4);
                    v.x += bv.x * bs; v.y += bv.y * bs; v.z += bv.z * bs; v.w += bv.w * bs;
                }
                if (a.o[w].addb) {
                    ushort4 ad = *(const ushort4*)(a.o[w].addb + rr * TT + c * 4);
                    v.x += bf2f(ad.x); v.y += bf2f(ad.y); v.z += bf2f(ad.z); v.w += bf2f(ad.w);
                }
                if (a.o[w].addf) {
                    float4 ad = *(const float4*)(a.o[w].addf + rr * TT + c * 4);
                    v.x += ad.x; v.y += ad.y; v.z += ad.z; v.w += ad.w;
                }
                if (a.o[w].cvec) {
                    float4 cv = *(const float4*)(a.o[w].cvec + (long)(rr / EE) * TT + c * 4);
                    v.x += cv.x; v.y += cv.y; v.z += cv.z; v.w += cv.w;
                }
                if (a.o[w].relu) {
                    v.x = fmaxf(v.x, 0.f); v.y = fmaxf(v.y, 0.f);
                    v.z = fmaxf(v.z, 0.f); v.w = fmaxf(v.w, 0.f);
                }
                if (a.o[w].y_bf16) {
                    ushort4 ov;
                    ov.x = f2bf(v.x); ov.y = f2bf(v.y); ov.z = f2bf(v.z); ov.w = f2bf(v.w);
                    *(ushort4*)((unsigned short*)a.o[w].Y + rr * TT + c * 4) = ov;
                } else {
                    *(float4*)((float*)a.o[w].Y + rr * TT + c * 4) = v;
                }
            }
        }
        __syncthreads();
    }
}

// ---------------------------------------------------------------- compose: C = A @ B, cb = A@ab + bb
__global__ __launch_bounds__(128)
void compose_kernel(const float* __restrict__ A, const float* __restrict__ B,
                    const float* __restrict__ ab, const float* __restrict__ bb,
                    float* __restrict__ C, float* __restrict__ cb) {
    int i = blockIdx.x, j = threadIdx.x;
    __shared__ float arow[TT];
    if (j < TT) arow[j] = A[i * TT + j];
    __syncthreads();
    if (j < TT) {
        float acc = 0.f;
        for (int k = 0; k < TT; ++k) acc += arow[k] * B[k * TT + j];
        C[i * TT + j] = acc;
    }
    if (j == 0) {
        float acc = bb[i];
        for (int k = 0; k < TT; ++k) acc += arow[k] * ab[k];
        cb[i] = acc;
    }
}

// ---------------------------------------------------------------- Wsc (fused sim/softmax/att)
__global__ __launch_bounds__(256)
void wsc_kernel(const float* __restrict__ qh_emb, const int* __restrict__ qtext,
                const unsigned short* __restrict__ ent_f, const int* __restrict__ rel,
                float* __restrict__ Wsc) {
    int b = blockIdx.x >> 4;
    int chunk = blockIdx.x & 15;
    __shared__ __align__(16) float qh[LQ_ * TT];
    __shared__ float msk[LQ_];
    for (int i = threadIdx.x; i < LQ_ * TT; i += 256) qh[i] = qh_emb[(long)b * LQ_ * TT + i];
    for (int i = threadIdx.x; i < LQ_; i += 256)
        msk[i] = (qtext[b * LQ_ + i] != 0) ? 0.f : VERY_NEG_;
    __syncthreads();
    int f = chunk * 256 + threadIdx.x;
    if (f >= FF) return;
    long bf = (long)b * FF + f;
    const unsigned short* fr = ent_f + (long)rel[bf] * TT;
    float sim[LQ_];
    #pragma unroll
    for (int l = 0; l < LQ_; ++l) sim[l] = 0.f;
    for (int kq = 0; kq < 25; ++kq) {
        ushort4 x4 = *(const ushort4*)(fr + kq * 4);
        float x0 = bf2f(x4.x), x1 = bf2f(x4.y), x2 = bf2f(x4.z), x3 = bf2f(x4.w);
        #pragma unroll
        for (int l = 0; l < LQ_; ++l) {
            float4 q = ((const float4*)(qh + l * TT))[kq];
            sim[l] += x0 * q.x + x1 * q.y + x2 * q.z + x3 * q.w;
        }
    }
    float mx = -INFINITY;
    #pragma unroll
    for (int l = 0; l < LQ_; ++l) {
        sim[l] *= 0.1f;  // /sqrt(100)
        mx = fmaxf(mx, sim[l] + msk[l]);
    }
    float ssum = 0.f, wsum = 0.f;
    #pragma unroll
    for (int l = 0; l < LQ_; ++l) {
        float p = expf(sim[l] + msk[l] - mx);
        ssum += p;
        wsum += p * sim[l];
    }
    Wsc[bf] = wsum / ssum;
}

// ---------------------------------------------------------------- row max over facts
__global__ __launch_bounds__(256)
void rowmax_kernel(const float* __restrict__ Wsc, float* __restrict__ bmax) {
    int b = blockIdx.x, tid = threadIdx.x;
    __shared__ float red[256];
    float m = -INFINITY;
    for (int f = tid; f < FF; f += 256) m = fmaxf(m, Wsc[(long)b * FF + f]);
    red[tid] = m;
    __syncthreads();
    for (int s = 128; s; s >>= 1) {
        if (tid < s) red[tid] = fmaxf(red[tid], red[tid + s]);
        __syncthreads();
    }
    if (tid == 0) bmax[b] = red[0];
}

// ---------------------------------------------------------------- W_tilde + e2f_softmax scatter + tail counts
__global__ __launch_bounds__(256)
void wtilde_kernel(const float* __restrict__ Wsc, const float* __restrict__ bmax,
                   const int* __restrict__ head, const int* __restrict__ tail,
                   float* __restrict__ W_tilde, float* __restrict__ e2f_sm,
                   float* __restrict__ cnt) {
    int idx = blockIdx.x * 256 + threadIdx.x;
    if (idx >= BB * FF) return;
    int b = idx / FF;
    float wt = expf(Wsc[idx] - bmax[b]);
    W_tilde[idx] = wt;
    atomicAdd(&e2f_sm[(long)b * EE + head[idx]], wt);
    atomicAdd(&cnt[(long)b * EE + tail[idx]], 1.f);
}

// ---------------------------------------------------------------- per-batch exclusive scan of cnt -> offs
__global__ __launch_bounds__(256)
void scan_kernel(const float* __restrict__ cnt, int* __restrict__ offs) {
    int b = blockIdx.x, tid = threadIdx.x;
    __shared__ int ls[256];
    int c0 = 0, c1 = 0, c2 = 0, c3 = 0;
    int start = tid * 4;
    if (start + 0 < EE) c0 = (int)cnt[(long)b * EE + start + 0];
    if (start + 1 < EE) c1 = (int)cnt[(long)b * EE + start + 1];
    if (start + 2 < EE) c2 = (int)cnt[(long)b * EE + start + 2];
    if (start + 3 < EE) c3 = (int)cnt[(long)b * EE + start + 3];
    int s = c0 + c1 + c2 + c3;
    ls[tid] = s;
    __syncthreads();
    for (int d = 1; d < 256; d <<= 1) {
        int v = (tid >= d) ? ls[tid - d] : 0;
        __syncthreads();
        ls[tid] += v;
        __syncthreads();
    }
    int excl = ls[tid] - s + b * FF;   // each batch owns exactly FF facts
    if (start + 0 < EE) { offs[(long)b * EE + start + 0] = excl; excl += c0; }
    if (start + 1 < EE) { offs[(long)b * EE + start + 1] = excl; excl += c1; }
    if (start + 2 < EE) { offs[(long)b * EE + start + 2] = excl; excl += c2; }
    if (start + 3 < EE) { offs[(long)b * EE + start + 3] = excl; excl += c3; }
    if (b == BB - 1 && tid == 255) offs[BB * EE] = BB * FF;
}

// ---------------------------------------------------------------- sort facts by tail; emit permuted metadata
// rh_perm[pos] = (rel, b*EE+head); wsm_perm[pos] = W_tilde / max(e2f_sm[head], EPS)  (layer-invariant)
__global__ __launch_bounds__(256)
void sortfacts_kernel(const int* __restrict__ tail, const int* __restrict__ head,
                      const int* __restrict__ rel, const float* __restrict__ W_tilde,
                      const float* __restrict__ e2f_sm, const int* __restrict__ offs,
                      int* __restrict__ fillc, int2* __restrict__ rh_perm,
                      float* __restrict__ wsm_perm) {
    int idx = blockIdx.x * 256 + threadIdx.x;
    if (idx >= BB * FF) return;
    int b = idx / FF;
    int bin = b * EE + tail[idx];
    int pos = offs[bin] + atomicAdd(&fillc[bin], 1);
    int bh = b * EE + head[idx];
    rh_perm[pos] = make_int2(rel[idx], bh);
    wsm_perm[pos] = W_tilde[idx] / fmaxf(e2f_sm[bh], EPS_);
}

// ---------------------------------------------------------------- segmented e2f + fused pagerank update
// per (b,tail) bin: eacc[bin,:] = sum_f relu(kbs[rel_f] + kbh[bh_f]) * n_f ; pr_nxt = 0.8*sum(n) + 0.2*pr_cur
__global__ __launch_bounds__(256)
void e2f_sorted_kernel(const unsigned short* __restrict__ kbs_tab,
                       const unsigned short* __restrict__ kbh,
                       const float* __restrict__ wsm_perm, const int2* __restrict__ rh_perm,
                       const float* __restrict__ pr_cur, const int* __restrict__ offs,
                       unsigned short* __restrict__ eaccb, float* __restrict__ pr_nxt,
                       float* __restrict__ pr_out) {
    int grp = threadIdx.x >> 7;        // 2 bins per block
    int t = threadIdx.x & 127;
    int bin = blockIdx.x * 2 + grp;
    int j0 = offs[bin], j1 = offs[bin + 1];
    float acc = 0.f, nsum = 0.f;
    int j = j0;
    for (; j + 2 <= j1; j += 2) {
        float w0 = wsm_perm[j], w1 = wsm_perm[j + 1];
        int2 rh0 = rh_perm[j];
        int2 rh1 = rh_perm[j + 1];
        float n0 = w0 * pr_cur[rh0.y];
        float n1 = w1 * pr_cur[rh1.y];
        nsum += n0 + n1;
        if ((n0 != 0.f) || (n1 != 0.f)) {       // wave-uniform
            if (t < TT) {
                float v0 = fmaxf(bf2f(kbs_tab[(long)rh0.x * TT + t]) +
                                 bf2f(kbh[(long)rh0.y * TT + t]), 0.f);
                float v1 = fmaxf(bf2f(kbs_tab[(long)rh1.x * TT + t]) +
                                 bf2f(kbh[(long)rh1.y * TT + t]), 0.f);
                acc += v0 * n0 + v1 * n1;
            }
        }
    }
    if (j < j1) {
        float w0 = wsm_perm[j];
        int2 rh0 = rh_perm[j];
        float n0 = w0 * pr_cur[rh0.y];
        nsum += n0;
        if (n0 != 0.f && t < TT) {
            float v0 = fmaxf(bf2f(kbs_tab[(long)rh0.x * TT + t]) +
                             bf2f(kbh[(long)rh0.y * TT + t]), 0.f);
            acc += v0 * n0;
        }
    }
    if (t < TT) eaccb[(long)bin * TT + t] = f2bf(acc);
    if (t == TT) {
        float pv = 0.8f * nsum + 0.2f * pr_cur[bin];
        pr_nxt[bin] = pv;
        if (pr_out) pr_out[bin] = pv;
    }
}

// ---------------------------------------------------------------- weighted reductions s1,s3,prsum
#define RCH 50
__global__ __launch_bounds__(128)
void reduce_kernel(const float* __restrict__ pr, const unsigned short* __restrict__ ent,
                   const int* __restrict__ gidx, const unsigned short* __restrict__ f2e,
                   float* __restrict__ s1, float* __restrict__ s3, float* __restrict__ prsum) {
    int b = blockIdx.x / (EE / RCH), ch = blockIdx.x % (EE / RCH);
    int e0 = ch * RCH, tid = threadIdx.x;
    __shared__ float prl[RCH];
    __shared__ long erow[RCH];
    if (tid < RCH) {
        long idx = (long)b * EE + e0 + tid;
        prl[tid] = pr[idx];
        erow[tid] = gidx ? (long)gidx[idx] : idx;
    }
    __syncthreads();
    if (tid == 0) {
        float s = 0.f;
        for (int e = 0; e < RCH; ++e) s += prl[e];
        if (s != 0.f) atomicAdd(&prsum[b], s);
    }
    if (tid < TT) {
        float a1 = 0.f, a3 = 0.f;
        for (int e = 0; e < RCH; ++e) {
            float p = prl[e];
            if (p != 0.f) {
                a1 += p * bf2f(ent[erow[e] * TT + tid]);
                a3 += p * bf2f(f2e[((long)b * EE + e0 + e) * TT + tid]);
            }
        }
        atomicAdd(&s1[b * TT + tid], a1);
        atomicAdd(&s3[b * TT + tid], a3);
    }
}

// ---------------------------------------------------------------- per-layer tiny: q2e_vec + cvecs
__global__ __launch_bounds__(128)
void qvec_kernel(const float* __restrict__ qnode,
                 const float* __restrict__ q2eW, const float* __restrict__ q2eb,
                 const float* __restrict__ e2eW, const float* __restrict__ e2eb,
                 const float* __restrict__ e2qW, const float* __restrict__ e2qb,
                 float* __restrict__ q2e_vec, float* __restrict__ cvec_e2e,
                 float* __restrict__ cvec_e2q) {
    int b = blockIdx.x, t = threadIdx.x;
    __shared__ float qn[TT], qv[TT];
    if (t < TT) qn[t] = qnode[b * TT + t];
    __syncthreads();
    if (t < TT) {
        float acc = q2eb[t];
        for (int k = 0; k < TT; ++k) acc += qn[k] * q2eW[t * TT + k];
        qv[t] = acc;
        q2e_vec[b * TT + t] = acc;
    }
    __syncthreads();
    if (t < TT) {
        float a1 = e2eb[t], a2 = e2qb[t];
        for (int k = 0; k < TT; ++k) {
            a1 += qv[k] * e2eW[(long)t * 300 + TT + k];
            a2 += qv[k] * e2qW[(long)t * 300 + TT + k];
        }
        cvec_e2e[b * TT + t] = a1;
        cvec_e2q[b * TT + t] = a2;
    }
}

// ---------------------------------------------------------------- qnode update
__global__ __launch_bounds__(128)
void qnode_kernel(const float* __restrict__ s1, const float* __restrict__ s3,
                  const float* __restrict__ prsum, const float* __restrict__ cvec_e2q,
                  const float* __restrict__ e2qW, float* __restrict__ qnode,
                  float* __restrict__ out2) {
    int b = blockIdx.x, t = threadIdx.x;
    __shared__ float s1l[TT], s3l[TT];
    if (t < TT) { s1l[t] = s1[b * TT + t]; s3l[t] = s3[b * TT + t]; }
    __syncthreads();
    if (t < TT) {
        float acc = prsum[b] * cvec_e2q[b * TT + t];
        const float* wr = e2qW + (long)t * 300;
        for (int k = 0; k < TT; ++k) acc += s1l[k] * wr[k] + s3l[k] * wr[200 + k];
        qnode[b * TT + t] = acc;
        if (out2) out2[b * TT + t] = acc;
    }
}

// ================================================================ host
extern "C" void kernel_launch(void* const* d_in, const int* in_sizes, int n_in,
                              void* d_out, int out_size, void* d_ws, size_t ws_size,
                              hipStream_t stream) {
    const float* word_emb   = (const float*)d_in[0];
    const float* entity_emb = (const float*)d_in[1];
    const float* ent_W      = (const float*)d_in[2];
    const float* ent_b      = (const float*)d_in[3];
    const float* lstm_Wih   = (const float*)d_in[4];
    const float* lstm_Whh   = (const float*)d_in[5];
    const float* lstm_bih   = (const float*)d_in[6];
    const float* lstm_bhh   = (const float*)d_in[7];
    const float* q2e_W      = (const float*)d_in[8];
    const float* q2e_b      = (const float*)d_in[9];
    const float* e2q_W      = (const float*)d_in[10];
    const float* e2q_b      = (const float*)d_in[11];
    const float* e2e_W      = (const float*)d_in[12];
    const float* e2e_b      = (const float*)d_in[13];
    const float* kbh_W      = (const float*)d_in[14];
    const float* kbh_b      = (const float*)d_in[15];
    const float* kbt_W      = (const float*)d_in[16];
    const float* kbt_b      = (const float*)d_in[17];
    const float* kbs_W      = (const float*)d_in[18];
    const float* kbs_b      = (const float*)d_in[19];
    const float* q2e_adj    = (const float*)d_in[20];
    const int* query_text   = (const int*)d_in[21];
    const int* local_entity = (const int*)d_in[22];
    const int* kb_fact_rel  = (const int*)d_in[23];
    const int* head_idx     = (const int*)d_in[24];
    const int* tail_idx     = (const int*)d_in[25];
    float* out = (float*)d_out;

    char* base = (char*)d_ws;
    size_t off = 0;
    auto alloc = [&](size_t bytes) {
        void* p = base + off;
        off = (off + bytes + 255) & ~(size_t)255;
        return p;
    };
    const size_t NE = (size_t)BB * EE;          // 64000
    unsigned short* emb_bf  = (unsigned short*)alloc((size_t)EV_ * TT * 2);
    unsigned short* ent_f   = (unsigned short*)alloc((size_t)EV_ * TT * 2);
    unsigned short* kbs0    = (unsigned short*)alloc((size_t)EV_ * TT * 2);
    unsigned short* kbs1    = (unsigned short*)alloc((size_t)EV_ * TT * 2);
    unsigned short* entB    = (unsigned short*)alloc(NE * TT * 2);
    unsigned short* kbh_bf  = (unsigned short*)alloc(NE * TT * 2);   // aliased as f2e
    unsigned short* kbs_e   = (unsigned short*)alloc(NE * TT * 2);
    unsigned short* tmp     = (unsigned short*)alloc(NE * TT * 2);
    unsigned short* eaccb   = (unsigned short*)alloc(NE * TT * 2);
    float* xw               = (float*)alloc((size_t)BB * LQ_ * G4 * 4);
    float* qh_emb           = (float*)alloc((size_t)BB * LQ_ * TT * 4);
    float* WihT             = (float*)alloc((size_t)G4 * EMB_ * 4);
    float* Wsc              = (float*)alloc((size_t)BB * FF * 4);
    float* W_tilde          = (float*)alloc((size_t)BB * FF * 4);
    float* bmaxb            = (float*)alloc(BB * 4);
    float* e2f_sm           = (float*)alloc(NE * 4);                 // contiguous with cnt
    float* cnt              = (float*)alloc(NE * 4);
    float* prA              = (float*)alloc(NE * 4);
    float* prB              = (float*)alloc(NE * 4);
    float* qnode            = (float*)alloc((size_t)BB * TT * 4);
    float* q2e_vec          = (float*)alloc((size_t)BB * TT * 4);
    float* cvec_e2e         = (float*)alloc((size_t)BB * TT * 4);
    float* cvec_e2q         = (float*)alloc((size_t)BB * TT * 4);
    float* s1               = (float*)alloc((size_t)BB * TT * 4);    // s1,s3,prsum contiguous
    float* s3               = (float*)alloc((size_t)BB * TT * 4);
    float* prsum            = (float*)alloc(BB * 4);
    float* Ckbs0            = (float*)alloc((size_t)TT * TT * 4);
    float* Ckbs1            = (float*)alloc((size_t)TT * TT * 4);
    float* cb0              = (float*)alloc(TT * 4);
    float* cb1              = (float*)alloc(TT * 4);
    int* offs               = (int*)alloc((NE + 1) * 4);
    int* fillc              = (int*)alloc(NE * 4);
    int2* rh_perm           = (int2*)alloc((size_t)BB * FF * 8);
    float* wsm_perm         = (float*)alloc((size_t)BB * FF * 4);
    unsigned short* f2e = kbh_bf;  // alias: kbh dead after e2f_sorted

    // ---- LSTM path
    transpose_kernel<<<(G4 * EMB_ + 255) / 256, 256, 0, stream>>>(lstm_Wih, WihT, G4, EMB_);
    xw_kernel<<<BB * LQ_ / 4, 256, 0, stream>>>(word_emb, query_text, WihT, lstm_bih, lstm_bhh, xw);
    lstm_kernel<<<BB, 512, 0, stream>>>(xw, lstm_Whh, qh_emb, qnode);

    // ---- composed vocab tables: ent_f, kbs0, kbs1 in ONE pass over bf16 entity_emb
    cvt_bf16_kernel<<<(EV_ * TT / 4 + 255) / 256, 256, 0, stream>>>(entity_emb, emb_bf,
                                                                    (long)EV_ * TT / 4);
    compose_kernel<<<TT, 128, 0, stream>>>(kbs_W, ent_W, ent_b, kbs_b, Ckbs0, cb0);
    compose_kernel<<<TT, 128, 0, stream>>>(kbs_W + TT * TT, ent_W, ent_b, kbs_b + TT,
                                           Ckbs1, cb1);
    {
        GArgs g{};
        g.X = emb_bf; g.x_bf16 = 1; g.gidx = nullptr; g.rows = EV_; g.nw = 3;
        g.o[0].W = ent_W; g.o[0].wstride = TT; g.o[0].bias = ent_b;
        g.o[0].Y = ent_f; g.o[0].y_bf16 = 1;
        g.o[1].W = Ckbs0; g.o[1].wstride = TT; g.o[1].bias = cb0;
        g.o[1].Y = kbs0; g.o[1].y_bf16 = 1;
        g.o[2].W = Ckbs1; g.o[2].wstride = TT; g.o[2].bias = cb1;
        g.o[2].Y = kbs1; g.o[2].y_bf16 = 1;
        gemm_multi_kernel<<<(EV_ + 63) / 64, 256, 0, stream>>>(g);
    }

    // ---- attention scores -> W_tilde, e2f_softmax, counts
    wsc_kernel<<<BB * 16, 256, 0, stream>>>(qh_emb, query_text, ent_f, kb_fact_rel, Wsc);
    rowmax_kernel<<<BB, 256, 0, stream>>>(Wsc, bmaxb);
    hipMemsetAsync(e2f_sm, 0, 2 * NE * 4, stream);
    wtilde_kernel<<<(BB * FF + 255) / 256, 256, 0, stream>>>(Wsc, bmaxb, head_idx, tail_idx,
                                                             W_tilde, e2f_sm, cnt);
    hipMemcpyAsync(prA, q2e_adj, NE * 4, hipMemcpyDeviceToDevice, stream);

    // ---- tail-sort the fact list (once; metadata is layer-invariant)
    scan_kernel<<<BB, 256, 0, stream>>>(cnt, offs);
    hipMemsetAsync(fillc, 0, NE * 4, stream);
    sortfacts_kernel<<<(BB * FF + 255) / 256, 256, 0, stream>>>(
        tail_idx, head_idx, kb_fact_rel, W_tilde, e2f_sm, offs, fillc, rh_perm, wsm_perm);

    // ---- GNN layers (pr ping-pong: prA -> prB -> prA)
    for (int i = 0; i < 2; ++i) {
        const unsigned short* kbs_tab = i ? kbs1 : kbs0;
        float* pr_cur = i ? prB : prA;
        float* pr_nxt = i ? prA : prB;
        qvec_kernel<<<BB, 128, 0, stream>>>(qnode, q2e_W + i * TT * TT, q2e_b + i * TT,
                                            e2e_W + i * TT * 300, e2e_b + i * TT,
                                            e2q_W + i * TT * 300, e2q_b + i * TT,
                                            q2e_vec, cvec_e2e, cvec_e2q);
        // one pass over ent_in: kbh, kbs_e, e2e-part1(tmp)
        {
            GArgs g{};
            g.X = i ? (const void*)entB : (const void*)ent_f;
            g.x_bf16 = 1;
            g.gidx = i ? nullptr : local_entity;
            g.rows = (long)NE; g.nw = 3;
            g.o[0].W = kbh_W + i * TT * TT; g.o[0].wstride = TT; g.o[0].bias = kbh_b + i * TT;
            g.o[0].Y = kbh_bf; g.o[0].y_bf16 = 1;
            g.o[1].W = kbs_W + i * TT * TT; g.o[1].wstride = TT; g.o[1].bias = kbs_b + i * TT;
            g.o[1].Y = kbs_e; g.o[1].y_bf16 = 1;
            g.o[2].W = e2e_W + i * TT * 300; g.o[2].wstride = 300;
            g.o[2].Y = tmp; g.o[2].y_bf16 = 1;
            gemm_multi_kernel<<<(int)(NE / 64), 256, 0, stream>>>(g);
        }
        // segmented e2f + fused pagerank update (writes every (b,e) row; no memset)
        e2f_sorted_kernel<<<(int)(NE / 2), 256, 0, stream>>>(
            kbs_tab, kbh_bf, wsm_perm, rh_perm, pr_cur, offs,
            eaccb, pr_nxt, (i == 1) ? out + 6406400 : nullptr);
        // f2e = relu(kbs_e + eacc@kbt.T + kbt_b*cnt)   (f2e aliases kbh_bf)
        {
            GArgs g{};
            g.X = eaccb; g.x_bf16 = 1; g.gidx = nullptr; g.rows = (long)NE; g.nw = 1;
            g.o[0].W = kbt_W + i * TT * TT; g.o[0].wstride = TT;
            g.o[0].bias = kbt_b + i * TT; g.o[0].bscale = cnt;
            g.o[0].addb = kbs_e;
            g.o[0].Y = (void*)f2e; g.o[0].y_bf16 = 1; g.o[0].relu = 1;
            gemm_multi_kernel<<<(int)(NE / 64), 256, 0, stream>>>(g);
        }
        hipMemsetAsync(s1, 0, (size_t)(2 * BB * TT + BB) * 4, stream);
        reduce_kernel<<<BB * (EE / RCH), 128, 0, stream>>>(
            pr_nxt, i ? entB : ent_f, i ? nullptr : local_entity, f2e, s1, s3, prsum);
        qnode_kernel<<<BB, 128, 0, stream>>>(s1, s3, prsum, cvec_e2q, e2q_W + i * TT * 300,
                                             qnode, (i == 1) ? out + 6400000 : nullptr);
        // ent_out = relu(tmp + f2e@W3.T + cvec_e2e)
        {
            GArgs g{};
            g.X = f2e; g.x_bf16 = 1; g.gidx = nullptr; g.rows = (long)NE; g.nw = 1;
            g.o[0].W = e2e_W + i * TT * 300 + 200; g.o[0].wstride = 300;
            g.o[0].addb = tmp; g.o[0].cvec = cvec_e2e; g.o[0].relu = 1;
            g.o[0].Y = i ? (void*)out : (void*)entB; g.o[0].y_bf16 = i ? 0 : 1;
            gemm_multi_kernel<<<(int)(NE / 64), 256, 0, stream>>>(g);
        }
    }
}